// Round 2
// baseline (1271.745 us; speedup 1.0000x reference)
//
#include <hip/hip_runtime.h>

// FHETinyGPT forward: emb-gather -> q/k/v proj -> QK^T+poly-act -> PV -> wo -> logits.
// All matmuls are bf16 MFMA gemm_bt (C = A * B^T, A[M,K], B[N,K], both row-major,
// K-contiguous), m97-structure: 128x128 tile, BK=32, 4 waves, global_load_lds w=16.
// R2: logits GEMM gets M-fastest tile order + XCD-chunked swizzle (B-panel L2/L3
// locality; A=16.8MB stays L3-hot) + nontemporal C stores (1GB stream, never re-read,
// was evicting B from L3 -> 2.27GB fetch vs 82MB ideal).

typedef __bf16 bf16_t;
typedef __bf16 bf16x8 __attribute__((ext_vector_type(8)));
typedef __bf16 bf16x4 __attribute__((ext_vector_type(4)));
typedef float  f32x4  __attribute__((ext_vector_type(4)));

#define VOCAB 32000
#define DIM   1024
#define BATCH 4
#define SEQ   2048
#define BT    (BATCH*SEQ)   // 8192

__device__ __forceinline__ void gload_lds16(const void* g, void* l) {
    __builtin_amdgcn_global_load_lds(
        (const __attribute__((address_space(1))) void*)g,
        (__attribute__((address_space(3))) void*)l,
        16, 0, 0);
}

// ---------------- weight cast f32 -> bf16 (vectorized float4 -> bf16x4) -------------
__global__ void cast_f32_to_bf16(const float* __restrict__ in, bf16_t* __restrict__ out, int n4) {
    int i = blockIdx.x * blockDim.x + threadIdx.x;
    if (i < n4) {
        float4 v = ((const float4*)in)[i];
        bf16x4 o;
        o.x = (bf16_t)v.x; o.y = (bf16_t)v.y; o.z = (bf16_t)v.z; o.w = (bf16_t)v.w;
        ((bf16x4*)out)[i] = o;
    }
}

// ---------------- h = emb_w[x] * 0.01 -> bf16 [BT, DIM] ----------------------------
__global__ void embed_gather(const int* __restrict__ x, const float* __restrict__ emb,
                             bf16_t* __restrict__ h) {
    const int tok = blockIdx.x;          // 0..BT-1
    const int row = x[tok];
    const float4* src = (const float4*)(emb + (long)row * DIM);
    bf16x4* dst = (bf16x4*)(h + (long)tok * DIM);
    int j = threadIdx.x;                 // 0..255 == DIM/4
    float4 v = src[j];
    bf16x4 o;
    o.x = (bf16_t)(v.x * 0.01f); o.y = (bf16_t)(v.y * 0.01f);
    o.z = (bf16_t)(v.z * 0.01f); o.w = (bf16_t)(v.w * 0.01f);
    dst[j] = o;
}

// ---------------- gemm_bt: C[M,N] = epi(scale * A[M,K] @ B[N,K]^T) ------------------
// 128x128 tile, BK=32, 256 threads = 4 waves (2x2), each wave 64x64 out (4x4 frags of
// 16x16x32 bf16 MFMA). A/B staged via global_load_lds dwordx4 into linear LDS.
// ACT:  0 = scale only; 1 = fhe_act(scale*acc) = 0.1 s^2 + 0.1 s.
// SWAP: 1 = grid is dim3(M/128, N/128); M-tile fastest + bijective XCD-chunked
//       swizzle (requires gridDim.x*gridDim.y % 8 == 0). 0 = grid dim3(N/128, M/128).
// NT:   1 = nontemporal C stores (C never re-read; don't pollute L2/L3).
template<int ACT, int SWAP, int NT, typename CT>
__global__ __launch_bounds__(256) void gemm_bt(
    const bf16_t* __restrict__ A, const bf16_t* __restrict__ B, CT* __restrict__ C,
    int M, int N, int K, long sA, long sB, long sC, float scale)
{
    __shared__ __align__(16) bf16_t lsA[128 * 32];
    __shared__ __align__(16) bf16_t lsB[128 * 32];

    const int bz = blockIdx.z;
    A += (long)bz * sA;  B += (long)bz * sB;  C += (long)bz * sC;

    int tm, tn;
    if (SWAP) {
        // linear dispatch index; XCD id ~ lin % 8 (round-robin dispatch)
        const int lin = blockIdx.y * gridDim.x + blockIdx.x;
        const int nwg = gridDim.x * gridDim.y;       // must be % 8 == 0
        const int q8  = nwg >> 3;
        const int swz = (lin & 7) * q8 + (lin >> 3); // contiguous work chunk per XCD
        tm = swz % gridDim.x;                        // M fastest -> B-panel reuse
        tn = swz / gridDim.x;
    } else {
        tm = blockIdx.y;  tn = blockIdx.x;
    }

    const int t = threadIdx.x;
    const int lane = t & 63, wave = t >> 6;
    const int wm = (wave >> 1) * 64;     // wave's row offset in 128-tile
    const int wn = (wave & 1) * 64;      // wave's col offset

    // staging: thread t loads 16B = 8 bf16; row = t/4 (+64 second call), col = (t%4)*8
    const int srow = t >> 2;
    const int scol = (t & 3) * 8;
    const bf16_t* gA = A + (long)(tm * 128 + srow) * K + scol;
    const bf16_t* gB = B + (long)(tn * 128 + srow) * K + scol;
    bf16_t* lA = &lsA[srow * 32 + scol];
    bf16_t* lB = &lsB[srow * 32 + scol];

    f32x4 acc[4][4];
#pragma unroll
    for (int i = 0; i < 4; ++i)
#pragma unroll
        for (int j = 0; j < 4; ++j)
            acc[i][j] = (f32x4){0.f, 0.f, 0.f, 0.f};

    const int arow = lane & 15;          // fragment row within 16
    const int acol = (lane >> 4) * 8;    // k-offset within 32

    for (int k0 = 0; k0 < K; k0 += 32) {
        __syncthreads();                 // all waves done reading previous tile
        gload_lds16(gA + k0,                lA);
        gload_lds16(gA + k0 + 64 * (long)K, lA + 64 * 32);
        gload_lds16(gB + k0,                lB);
        gload_lds16(gB + k0 + 64 * (long)K, lB + 64 * 32);
        __syncthreads();                 // compiler drains vmcnt(0) before barrier

        bf16x8 af[4], bfr[4];
#pragma unroll
        for (int i = 0; i < 4; ++i) {
            af[i]  = *(const bf16x8*)&lsA[(wm + i * 16 + arow) * 32 + acol];
            bfr[i] = *(const bf16x8*)&lsB[(wn + i * 16 + arow) * 32 + acol];
        }
#pragma unroll
        for (int i = 0; i < 4; ++i)
#pragma unroll
            for (int j = 0; j < 4; ++j)
                acc[i][j] = __builtin_amdgcn_mfma_f32_16x16x32_bf16(af[i], bfr[j], acc[i][j], 0, 0, 0);
    }

    // epilogue: C/D layout (m89/m91-verified): col = lane&15, row = (lane>>4)*4 + reg
    const int crow0 = tm * 128 + wm + (lane >> 4) * 4;
    const int ccol0 = tn * 128 + wn + (lane & 15);
#pragma unroll
    for (int i = 0; i < 4; ++i)
#pragma unroll
        for (int j = 0; j < 4; ++j)
#pragma unroll
            for (int r = 0; r < 4; ++r) {
                float s = acc[i][j][r] * scale;
                if (ACT) s = s * s * 0.1f + s * 0.1f;
                CT* p = &C[(long)(crow0 + i * 16 + r) * N + (ccol0 + j * 16)];
                if (NT) __builtin_nontemporal_store((CT)s, p);
                else    *p = (CT)s;
            }
}

// -----------------------------------------------------------------------------------
extern "C" void kernel_launch(void* const* d_in, const int* in_sizes, int n_in,
                              void* d_out, int out_size, void* d_ws, size_t ws_size,
                              hipStream_t stream) {
    const int*   x    = (const int*)d_in[0];
    const float* emb  = (const float*)d_in[1];
    const float* wq   = (const float*)d_in[2];
    const float* wk   = (const float*)d_in[3];
    const float* wv   = (const float*)d_in[4];
    const float* wo   = (const float*)d_in[5];
    const float* wout = (const float*)d_in[6];
    float* logits = (float*)d_out;

    char* ws = (char*)d_ws;
    size_t off = 0;
    auto alloc = [&](size_t bytes) {
        char* p = ws + off;
        off += (bytes + 255) & ~(size_t)255;
        return p;
    };
    bf16_t* hb    = (bf16_t*)alloc((size_t)BT * DIM * 2);        // h   [8192,1024]
    bf16_t* qb    = (bf16_t*)alloc((size_t)BT * DIM * 2);        // q
    bf16_t* kb    = (bf16_t*)alloc((size_t)BT * DIM * 2);        // k
    bf16_t* vtb   = (bf16_t*)alloc((size_t)BATCH * DIM * SEQ * 2); // v^T [b][1024,2048]
    bf16_t* attnb = (bf16_t*)alloc((size_t)BATCH * SEQ * SEQ * 2); // act(attn) [b][2048,2048]
    bf16_t* o1b   = (bf16_t*)alloc((size_t)BT * DIM * 2);        // PV out
    bf16_t* o2b   = (bf16_t*)alloc((size_t)BT * DIM * 2);        // after wo
    bf16_t* wqb   = (bf16_t*)alloc((size_t)DIM * DIM * 2);
    bf16_t* wkb   = (bf16_t*)alloc((size_t)DIM * DIM * 2);
    bf16_t* wvb   = (bf16_t*)alloc((size_t)DIM * DIM * 2);
    bf16_t* wob   = (bf16_t*)alloc((size_t)DIM * DIM * 2);
    bf16_t* woutb = (bf16_t*)alloc((size_t)VOCAB * DIM * 2);

    // weight casts
    {
        int n4 = DIM * DIM / 4;                     // 262144 -> 1024 blocks
        cast_f32_to_bf16<<<n4 / 256, 256, 0, stream>>>(wq, wqb, n4);
        cast_f32_to_bf16<<<n4 / 256, 256, 0, stream>>>(wk, wkb, n4);
        cast_f32_to_bf16<<<n4 / 256, 256, 0, stream>>>(wv, wvb, n4);
        cast_f32_to_bf16<<<n4 / 256, 256, 0, stream>>>(wo, wob, n4);
        int n4o = VOCAB * DIM / 4;                  // 8192000 -> 32000 blocks
        cast_f32_to_bf16<<<n4o / 256, 256, 0, stream>>>(wout, woutb, n4o);
    }

    // h = emb[x] * 0.01
    embed_gather<<<BT, 256, 0, stream>>>(x, emb, hb);

    dim3 blk(256);
    // q = (h @ wq^T) * 0.01 ; k likewise                 [8192,1024]
    gemm_bt<0, 0, 0, bf16_t><<<dim3(DIM / 128, BT / 128, 1), blk, 0, stream>>>(
        hb, wqb, qb, BT, DIM, DIM, 0, 0, 0, 0.01f);
    gemm_bt<0, 0, 0, bf16_t><<<dim3(DIM / 128, BT / 128, 1), blk, 0, stream>>>(
        hb, wkb, kb, BT, DIM, DIM, 0, 0, 0, 0.01f);
    // v^T[b][d,s] = 0.1 * sum_e wv[d,e] h[b,s,e]         [1024,2048] per batch
    gemm_bt<0, 0, 0, bf16_t><<<dim3(SEQ / 128, DIM / 128, BATCH), blk, 0, stream>>>(
        wvb, hb, vtb, DIM, SEQ, DIM, 0, (long)SEQ * DIM, (long)DIM * SEQ, 0.1f);
    // attn = fhe_act(0.01 * q[b] @ k[b]^T)               [2048,2048] per batch
    gemm_bt<1, 0, 0, bf16_t><<<dim3(SEQ / 128, SEQ / 128, BATCH), blk, 0, stream>>>(
        qb, kb, attnb, SEQ, SEQ, DIM,
        (long)SEQ * DIM, (long)SEQ * DIM, (long)SEQ * SEQ, 0.01f);
    // o1 = 0.01 * attn[b] @ vT[b]^T                      [2048,1024] per batch
    gemm_bt<0, 0, 0, bf16_t><<<dim3(DIM / 128, SEQ / 128, BATCH), blk, 0, stream>>>(
        attnb, vtb, o1b, SEQ, DIM, SEQ,
        (long)SEQ * SEQ, (long)DIM * SEQ, (long)SEQ * DIM, 0.01f);
    // o2 = 0.1 * o1 @ wo^T                               [8192,1024]
    gemm_bt<0, 0, 0, bf16_t><<<dim3(DIM / 128, BT / 128, 1), blk, 0, stream>>>(
        o1b, wob, o2b, BT, DIM, DIM, 0, 0, 0, 0.1f);
    // logits = o2 @ wout^T  -> f32 d_out                 [8192,32000]
    // SWAP grid: dim3(M-tiles, N-tiles) = (64, 250); nwg=16000 % 8 == 0 (bijective).
    gemm_bt<0, 1, 1, float><<<dim3(BT / 128, VOCAB / 128, 1), blk, 0, stream>>>(
        o2b, woutb, logits, BT, VOCAB, DIM, 0, 0, 0, 1.0f);
}

// Round 3
// 1158.988 us; speedup vs baseline: 1.0973x; 1.0973x over previous
//
#include <hip/hip_runtime.h>

// FHETinyGPT forward: emb-gather -> q/k/v proj -> QK^T+poly-act -> PV -> wo -> logits.
// All matmuls are bf16 MFMA gemm_bt (C = A * B^T, A[M,K], B[N,K], both row-major,
// K-contiguous), m97-structure: 128x128 tile, BK=32, 4 waves, global_load_lds w=16.
// R3: logits GEMM uses 2-D band swizzle: XCD k owns tm-band [8k,8k+8) (A-band 2MB,
// L2-resident), sweeps tn with tm-inner-8 (B-panel 8x L2 reuse; XCDs in-phase on B
// -> L3 reuse). NT stores reverted (R2: WRITE_SIZE +29%, sub-line HBM writes).

typedef __bf16 bf16_t;
typedef __bf16 bf16x8 __attribute__((ext_vector_type(8)));
typedef __bf16 bf16x4 __attribute__((ext_vector_type(4)));
typedef float  f32x4  __attribute__((ext_vector_type(4)));

#define VOCAB 32000
#define DIM   1024
#define BATCH 4
#define SEQ   2048
#define BT    (BATCH*SEQ)   // 8192

__device__ __forceinline__ void gload_lds16(const void* g, void* l) {
    __builtin_amdgcn_global_load_lds(
        (const __attribute__((address_space(1))) void*)g,
        (__attribute__((address_space(3))) void*)l,
        16, 0, 0);
}

// ---------------- weight cast f32 -> bf16 (vectorized float4 -> bf16x4) -------------
__global__ void cast_f32_to_bf16(const float* __restrict__ in, bf16_t* __restrict__ out, int n4) {
    int i = blockIdx.x * blockDim.x + threadIdx.x;
    if (i < n4) {
        float4 v = ((const float4*)in)[i];
        bf16x4 o;
        o.x = (bf16_t)v.x; o.y = (bf16_t)v.y; o.z = (bf16_t)v.z; o.w = (bf16_t)v.w;
        ((bf16x4*)out)[i] = o;
    }
}

// ---------------- h = emb_w[x] * 0.01 -> bf16 [BT, DIM] ----------------------------
__global__ void embed_gather(const int* __restrict__ x, const float* __restrict__ emb,
                             bf16_t* __restrict__ h) {
    const int tok = blockIdx.x;          // 0..BT-1
    const int row = x[tok];
    const float4* src = (const float4*)(emb + (long)row * DIM);
    bf16x4* dst = (bf16x4*)(h + (long)tok * DIM);
    int j = threadIdx.x;                 // 0..255 == DIM/4
    float4 v = src[j];
    bf16x4 o;
    o.x = (bf16_t)(v.x * 0.01f); o.y = (bf16_t)(v.y * 0.01f);
    o.z = (bf16_t)(v.z * 0.01f); o.w = (bf16_t)(v.w * 0.01f);
    dst[j] = o;
}

// ---------------- gemm_bt: C[M,N] = epi(scale * A[M,K] @ B[N,K]^T) ------------------
// 128x128 tile, BK=32, 256 threads = 4 waves (2x2), each wave 64x64 out (4x4 frags of
// 16x16x32 bf16 MFMA). A/B staged via global_load_lds dwordx4 into linear LDS.
// ACT: 0 = scale only; 1 = fhe_act(scale*acc) = 0.1 s^2 + 0.1 s.
// SWZ: 0 = natural grid dim3(N/128, M/128).
//      2 = band swizzle; grid MUST be dim3(M/128, N/128) with M/128 == 64:
//          XCD k (= dispatch_lin & 7) owns tm in [8k, 8k+8); within the band,
//          tm-inner-8, tn-outer. A-band (8 tiles = 2MB) stays L2-resident; each
//          B-panel (256KB) is reused by 8 consecutive blocks on the same XCD.
template<int ACT, int SWZ, typename CT>
__global__ __launch_bounds__(256) void gemm_bt(
    const bf16_t* __restrict__ A, const bf16_t* __restrict__ B, CT* __restrict__ C,
    int M, int N, int K, long sA, long sB, long sC, float scale)
{
    __shared__ __align__(16) bf16_t lsA[128 * 32];
    __shared__ __align__(16) bf16_t lsB[128 * 32];

    const int bz = blockIdx.z;
    A += (long)bz * sA;  B += (long)bz * sB;  C += (long)bz * sC;

    int tm, tn;
    if (SWZ == 2) {
        const int lin = blockIdx.y * gridDim.x + blockIdx.x;  // hw dispatch order
        const int xcd = lin & 7;                              // round-robin XCD id
        const int j   = lin >> 3;                             // 0..nwg/8-1
        tm = (xcd << 3) | (j & 7);                            // band k, tm-inner-8
        tn = j >> 3;
    } else {
        tm = blockIdx.y;  tn = blockIdx.x;
    }

    const int t = threadIdx.x;
    const int lane = t & 63, wave = t >> 6;
    const int wm = (wave >> 1) * 64;     // wave's row offset in 128-tile
    const int wn = (wave & 1) * 64;      // wave's col offset

    // staging: thread t loads 16B = 8 bf16; row = t/4 (+64 second call), col = (t%4)*8
    const int srow = t >> 2;
    const int scol = (t & 3) * 8;
    const bf16_t* gA = A + (long)(tm * 128 + srow) * K + scol;
    const bf16_t* gB = B + (long)(tn * 128 + srow) * K + scol;
    bf16_t* lA = &lsA[srow * 32 + scol];
    bf16_t* lB = &lsB[srow * 32 + scol];

    f32x4 acc[4][4];
#pragma unroll
    for (int i = 0; i < 4; ++i)
#pragma unroll
        for (int j = 0; j < 4; ++j)
            acc[i][j] = (f32x4){0.f, 0.f, 0.f, 0.f};

    const int arow = lane & 15;          // fragment row within 16
    const int acol = (lane >> 4) * 8;    // k-offset within 32

    for (int k0 = 0; k0 < K; k0 += 32) {
        __syncthreads();                 // all waves done reading previous tile
        gload_lds16(gA + k0,                lA);
        gload_lds16(gA + k0 + 64 * (long)K, lA + 64 * 32);
        gload_lds16(gB + k0,                lB);
        gload_lds16(gB + k0 + 64 * (long)K, lB + 64 * 32);
        __syncthreads();                 // compiler drains vmcnt(0) before barrier

        bf16x8 af[4], bfr[4];
#pragma unroll
        for (int i = 0; i < 4; ++i) {
            af[i]  = *(const bf16x8*)&lsA[(wm + i * 16 + arow) * 32 + acol];
            bfr[i] = *(const bf16x8*)&lsB[(wn + i * 16 + arow) * 32 + acol];
        }
#pragma unroll
        for (int i = 0; i < 4; ++i)
#pragma unroll
            for (int j = 0; j < 4; ++j)
                acc[i][j] = __builtin_amdgcn_mfma_f32_16x16x32_bf16(af[i], bfr[j], acc[i][j], 0, 0, 0);
    }

    // epilogue: C/D layout (m89/m91-verified): col = lane&15, row = (lane>>4)*4 + reg
    const int crow0 = tm * 128 + wm + (lane >> 4) * 4;
    const int ccol0 = tn * 128 + wn + (lane & 15);
#pragma unroll
    for (int i = 0; i < 4; ++i)
#pragma unroll
        for (int j = 0; j < 4; ++j)
#pragma unroll
            for (int r = 0; r < 4; ++r) {
                float s = acc[i][j][r] * scale;
                if (ACT) s = s * s * 0.1f + s * 0.1f;
                C[(long)(crow0 + i * 16 + r) * N + (ccol0 + j * 16)] = (CT)s;
            }
}

// -----------------------------------------------------------------------------------
extern "C" void kernel_launch(void* const* d_in, const int* in_sizes, int n_in,
                              void* d_out, int out_size, void* d_ws, size_t ws_size,
                              hipStream_t stream) {
    const int*   x    = (const int*)d_in[0];
    const float* emb  = (const float*)d_in[1];
    const float* wq   = (const float*)d_in[2];
    const float* wk   = (const float*)d_in[3];
    const float* wv   = (const float*)d_in[4];
    const float* wo   = (const float*)d_in[5];
    const float* wout = (const float*)d_in[6];
    float* logits = (float*)d_out;

    char* ws = (char*)d_ws;
    size_t off = 0;
    auto alloc = [&](size_t bytes) {
        char* p = ws + off;
        off += (bytes + 255) & ~(size_t)255;
        return p;
    };
    bf16_t* hb    = (bf16_t*)alloc((size_t)BT * DIM * 2);        // h   [8192,1024]
    bf16_t* qb    = (bf16_t*)alloc((size_t)BT * DIM * 2);        // q
    bf16_t* kb    = (bf16_t*)alloc((size_t)BT * DIM * 2);        // k
    bf16_t* vtb   = (bf16_t*)alloc((size_t)BATCH * DIM * SEQ * 2); // v^T [b][1024,2048]
    bf16_t* attnb = (bf16_t*)alloc((size_t)BATCH * SEQ * SEQ * 2); // act(attn) [b][2048,2048]
    bf16_t* o1b   = (bf16_t*)alloc((size_t)BT * DIM * 2);        // PV out
    bf16_t* o2b   = (bf16_t*)alloc((size_t)BT * DIM * 2);        // after wo
    bf16_t* wqb   = (bf16_t*)alloc((size_t)DIM * DIM * 2);
    bf16_t* wkb   = (bf16_t*)alloc((size_t)DIM * DIM * 2);
    bf16_t* wvb   = (bf16_t*)alloc((size_t)DIM * DIM * 2);
    bf16_t* wob   = (bf16_t*)alloc((size_t)DIM * DIM * 2);
    bf16_t* woutb = (bf16_t*)alloc((size_t)VOCAB * DIM * 2);

    // weight casts
    {
        int n4 = DIM * DIM / 4;                     // 262144 -> 1024 blocks
        cast_f32_to_bf16<<<n4 / 256, 256, 0, stream>>>(wq, wqb, n4);
        cast_f32_to_bf16<<<n4 / 256, 256, 0, stream>>>(wk, wkb, n4);
        cast_f32_to_bf16<<<n4 / 256, 256, 0, stream>>>(wv, wvb, n4);
        cast_f32_to_bf16<<<n4 / 256, 256, 0, stream>>>(wo, wob, n4);
        int n4o = VOCAB * DIM / 4;                  // 8192000 -> 32000 blocks
        cast_f32_to_bf16<<<n4o / 256, 256, 0, stream>>>(wout, woutb, n4o);
    }

    // h = emb[x] * 0.01
    embed_gather<<<BT, 256, 0, stream>>>(x, emb, hb);

    dim3 blk(256);
    // q = (h @ wq^T) * 0.01 ; k likewise                 [8192,1024]
    gemm_bt<0, 0, bf16_t><<<dim3(DIM / 128, BT / 128, 1), blk, 0, stream>>>(
        hb, wqb, qb, BT, DIM, DIM, 0, 0, 0, 0.01f);
    gemm_bt<0, 0, bf16_t><<<dim3(DIM / 128, BT / 128, 1), blk, 0, stream>>>(
        hb, wkb, kb, BT, DIM, DIM, 0, 0, 0, 0.01f);
    // v^T[b][d,s] = 0.1 * sum_e wv[d,e] h[b,s,e]         [1024,2048] per batch
    gemm_bt<0, 0, bf16_t><<<dim3(SEQ / 128, DIM / 128, BATCH), blk, 0, stream>>>(
        wvb, hb, vtb, DIM, SEQ, DIM, 0, (long)SEQ * DIM, (long)DIM * SEQ, 0.1f);
    // attn = fhe_act(0.01 * q[b] @ k[b]^T)               [2048,2048] per batch
    gemm_bt<1, 0, bf16_t><<<dim3(SEQ / 128, SEQ / 128, BATCH), blk, 0, stream>>>(
        qb, kb, attnb, SEQ, SEQ, DIM,
        (long)SEQ * DIM, (long)SEQ * DIM, (long)SEQ * SEQ, 0.01f);
    // o1 = 0.01 * attn[b] @ vT[b]^T                      [2048,1024] per batch
    gemm_bt<0, 0, bf16_t><<<dim3(DIM / 128, SEQ / 128, BATCH), blk, 0, stream>>>(
        attnb, vtb, o1b, SEQ, DIM, SEQ,
        (long)SEQ * SEQ, (long)DIM * SEQ, (long)SEQ * DIM, 0.01f);
    // o2 = 0.1 * o1 @ wo^T                               [8192,1024]
    gemm_bt<0, 0, bf16_t><<<dim3(DIM / 128, BT / 128, 1), blk, 0, stream>>>(
        o1b, wob, o2b, BT, DIM, DIM, 0, 0, 0, 0.1f);
    // logits = o2 @ wout^T  -> f32 d_out                 [8192,32000]
    // SWZ=2 grid: dim3(M-tiles=64, N-tiles=250); nwg=16000, 64 = 8 XCD x 8 band.
    gemm_bt<0, 2, float><<<dim3(BT / 128, VOCAB / 128, 1), blk, 0, stream>>>(
        o2b, woutb, logits, BT, VOCAB, DIM, 0, 0, 0, 1.0f);
}

// Round 4
// 997.666 us; speedup vs baseline: 1.2747x; 1.1617x over previous
//
#include <hip/hip_runtime.h>

// FHETinyGPT forward: emb-gather -> q/k/v proj -> QK^T+poly-act -> PV -> wo -> logits.
// Small/medium matmuls: proven m97-structure gemm_bt (128x128, BK=32, 4 waves).
// Logits GEMM (74% of runtime): 256x256 8-phase pipelined kernel (T2 swizzle +
// T3/T4 counted vmcnt + T5 setprio), derived from the m201 template:
//   - 8 waves (2M x 4N), per-wave 128x64 out, quadrant phases (mh,nh) read exactly
//     A-half mh + B-half nh (wave rows = mh*128 + wm*64).
//   - LDS 128KB = 2 buf x {A,B} x 2 halves x (128x64 bf16). Swizzle o^=((o>>7)&3)<<4
//     => conflict-free (2/bank) ds_read_b128; staging pre-applies the same involution
//     to the global source (linear LDS dest for global_load_lds).
//   - Stage duties: q0 -> tile t+1 h1s (idle buffer); q2/q3 -> tile t+2 h0s (freed
//     halves of current buffer). vmcnt(4) once per K-tile => all of tile t+1 landed.

typedef __bf16 bf16_t;
typedef __bf16 bf16x8 __attribute__((ext_vector_type(8)));
typedef __bf16 bf16x4 __attribute__((ext_vector_type(4)));
typedef float  f32x4  __attribute__((ext_vector_type(4)));

#define VOCAB 32000
#define DIM   1024
#define BATCH 4
#define SEQ   2048
#define BT    (BATCH*SEQ)   // 8192

__device__ __forceinline__ void gload_lds16(const void* g, void* l) {
    __builtin_amdgcn_global_load_lds(
        (const __attribute__((address_space(1))) void*)g,
        (__attribute__((address_space(3))) void*)l,
        16, 0, 0);
}

// ---------------- weight cast f32 -> bf16 ------------------------------------------
__global__ void cast_f32_to_bf16(const float* __restrict__ in, bf16_t* __restrict__ out, int n4) {
    int i = blockIdx.x * blockDim.x + threadIdx.x;
    if (i < n4) {
        float4 v = ((const float4*)in)[i];
        bf16x4 o;
        o.x = (bf16_t)v.x; o.y = (bf16_t)v.y; o.z = (bf16_t)v.z; o.w = (bf16_t)v.w;
        ((bf16x4*)out)[i] = o;
    }
}

// ---------------- h = emb_w[x] * 0.01 -> bf16 [BT, DIM] ----------------------------
__global__ void embed_gather(const int* __restrict__ x, const float* __restrict__ emb,
                             bf16_t* __restrict__ h) {
    const int tok = blockIdx.x;
    const int row = x[tok];
    const float4* src = (const float4*)(emb + (long)row * DIM);
    bf16x4* dst = (bf16x4*)(h + (long)tok * DIM);
    int j = threadIdx.x;
    float4 v = src[j];
    bf16x4 o;
    o.x = (bf16_t)(v.x * 0.01f); o.y = (bf16_t)(v.y * 0.01f);
    o.z = (bf16_t)(v.z * 0.01f); o.w = (bf16_t)(v.w * 0.01f);
    dst[j] = o;
}

// ---------------- gemm_bt (m97-structure, for the small/medium matmuls) ------------
template<int ACT, typename CT>
__global__ __launch_bounds__(256) void gemm_bt(
    const bf16_t* __restrict__ A, const bf16_t* __restrict__ B, CT* __restrict__ C,
    int M, int N, int K, long sA, long sB, long sC, float scale)
{
    __shared__ __align__(16) bf16_t lsA[128 * 32];
    __shared__ __align__(16) bf16_t lsB[128 * 32];

    const int bz = blockIdx.z;
    A += (long)bz * sA;  B += (long)bz * sB;  C += (long)bz * sC;

    const int tm = blockIdx.y, tn = blockIdx.x;
    const int t = threadIdx.x;
    const int lane = t & 63, wave = t >> 6;
    const int wm = (wave >> 1) * 64;
    const int wn = (wave & 1) * 64;

    const int srow = t >> 2;
    const int scol = (t & 3) * 8;
    const bf16_t* gA = A + (long)(tm * 128 + srow) * K + scol;
    const bf16_t* gB = B + (long)(tn * 128 + srow) * K + scol;
    bf16_t* lA = &lsA[srow * 32 + scol];
    bf16_t* lB = &lsB[srow * 32 + scol];

    f32x4 acc[4][4];
#pragma unroll
    for (int i = 0; i < 4; ++i)
#pragma unroll
        for (int j = 0; j < 4; ++j)
            acc[i][j] = (f32x4){0.f, 0.f, 0.f, 0.f};

    const int arow = lane & 15;
    const int acol = (lane >> 4) * 8;

    for (int k0 = 0; k0 < K; k0 += 32) {
        __syncthreads();
        gload_lds16(gA + k0,                lA);
        gload_lds16(gA + k0 + 64 * (long)K, lA + 64 * 32);
        gload_lds16(gB + k0,                lB);
        gload_lds16(gB + k0 + 64 * (long)K, lB + 64 * 32);
        __syncthreads();

        bf16x8 af[4], bfr[4];
#pragma unroll
        for (int i = 0; i < 4; ++i) {
            af[i]  = *(const bf16x8*)&lsA[(wm + i * 16 + arow) * 32 + acol];
            bfr[i] = *(const bf16x8*)&lsB[(wn + i * 16 + arow) * 32 + acol];
        }
#pragma unroll
        for (int i = 0; i < 4; ++i)
#pragma unroll
            for (int j = 0; j < 4; ++j)
                acc[i][j] = __builtin_amdgcn_mfma_f32_16x16x32_bf16(af[i], bfr[j], acc[i][j], 0, 0, 0);
    }

    const int crow0 = tm * 128 + wm + (lane >> 4) * 4;
    const int ccol0 = tn * 128 + wn + (lane & 15);
#pragma unroll
    for (int i = 0; i < 4; ++i)
#pragma unroll
        for (int j = 0; j < 4; ++j)
#pragma unroll
            for (int r = 0; r < 4; ++r) {
                float s = acc[i][j][r] * scale;
                if (ACT) s = s * s * 0.1f + s * 0.1f;
                C[(long)(crow0 + i * 16 + r) * N + (ccol0 + j * 16)] = (CT)s;
            }
}

// ---------------- 256x256 8-phase GEMM: C[M,N] = scale * A[M,K] @ B[N,K]^T ---------
// Requires: M % 256 == 0, M/256 == 32 (band swizzle), N % 256 == 0, K % 128 == 0.
// Grid: 1-D, (M/256)*(N/256) blocks of 512 threads.
__global__ __launch_bounds__(512, 2) void gemm_bt_256(
    const bf16_t* __restrict__ A, const bf16_t* __restrict__ B, float* __restrict__ C,
    int N, int K, float scale)
{
    __shared__ __align__(16) char smem[131072];   // 2buf x (A 32KB + B 32KB)
    char* const sm = smem;

    // band swizzle: XCD k owns tm in [4k, 4k+4); tm-inner-4, tn-outer.
    const int lin = blockIdx.x;
    const int xcd = lin & 7, jj = lin >> 3;
    const int tm = xcd * 4 + (jj & 3);
    const int tn = jj >> 2;
    const long trow0 = (long)tm * 256, tcol0 = (long)tn * 256;

    const int tid  = threadIdx.x;
    const int lane = tid & 63;
    const int wave = tid >> 6;
    const int wm = wave >> 2;            // 0..1  (M half owner within quadrant)
    const int wn = wave & 3;             // 0..3
    const int lr = lane & 15;
    const int ko2 = (lane >> 4) * 16;    // byte offset of this lane's 16B k-chunk
    // swizzled per-thread byte offset within a 1KB subtile (involution on bits 4-5)
    const int rbase = lr * 64 + (ko2 ^ (((lr >> 1) & 3) << 4));

    // staging decode: physical slot o (linear, thread t -> o=t*16 / 8192+t*16)
    // holds logical slot sigma(o); decode to (row-in-half, col-in-BK).
    const int o0 = tid * 16, o1 = 8192 + tid * 16;
    int sr0, sc0, sr1, sc1;
    {
        int ol = o0 ^ (((o0 >> 7) & 3) << 4);
        sr0 = ((ol >> 10) >> 1) * 16 + ((ol >> 6) & 15);
        sc0 = ((ol >> 10) & 1) * 32 + ((ol & 63) >> 1);
        ol = o1 ^ (((o1 >> 7) & 3) << 4);
        sr1 = ((ol >> 10) >> 1) * 16 + ((ol >> 6) & 15);
        sc1 = ((ol >> 10) & 1) * 32 + ((ol & 63) >> 1);
    }

    const bf16_t* Abase = A + trow0 * K;
    const bf16_t* Bbase = B + tcol0 * K;

    // stage one half-tile (128 rows x 64 cols) of K-tile kt into LDS half at ldsh
#define STAGE_HT(gbase, kt, half, ldsh) do {                                          \
    gload_lds16((gbase) + (long)((half) * 128 + sr0) * K + ((kt) * 64 + sc0), (ldsh) + o0); \
    gload_lds16((gbase) + (long)((half) * 128 + sr1) * K + ((kt) * 64 + sc1), (ldsh) + o1); \
} while (0)

    f32x4 acc[8][4];
#pragma unroll
    for (int i = 0; i < 8; ++i)
#pragma unroll
        for (int j = 0; j < 4; ++j)
            acc[i][j] = (f32x4){0.f, 0.f, 0.f, 0.f};

    // quadrant phase: reads A-half mh, B-half nh of current buffer; STAGECODE issues
    // prefetch; barrier; drain lds; prio-wrapped 16 MFMA. (post-MFMA barrier emitted
    // by caller so q3 can insert its vmcnt first.)
#define PHASE(mh, nh, ...) do {                                                       \
    bf16x8 af_[4][2], bv_[2][2];                                                      \
    _Pragma("unroll")                                                                 \
    for (int i_ = 0; i_ < 4; ++i_) {                                                  \
        _Pragma("unroll")                                                             \
        for (int ks_ = 0; ks_ < 2; ++ks_)                                             \
            af_[i_][ks_] = *(const bf16x8*)(ldsA + (mh) * 16384 +                     \
                               ((wm * 4 + i_) * 2 + ks_) * 1024 + rbase);             \
    }                                                                                 \
    _Pragma("unroll")                                                                 \
    for (int j_ = 0; j_ < 2; ++j_) {                                                  \
        _Pragma("unroll")                                                             \
        for (int ks_ = 0; ks_ < 2; ++ks_)                                             \
            bv_[j_][ks_] = *(const bf16x8*)(ldsB + (nh) * 16384 +                     \
                               ((wn * 2 + j_) * 2 + ks_) * 1024 + rbase);             \
    }                                                                                 \
    __VA_ARGS__;                                                                      \
    asm volatile("s_barrier" ::: "memory");                                           \
    asm volatile("s_waitcnt lgkmcnt(0)" ::: "memory");                                \
    __builtin_amdgcn_s_setprio(1);                                                    \
    _Pragma("unroll")                                                                 \
    for (int i_ = 0; i_ < 4; ++i_)                                                    \
        _Pragma("unroll")                                                             \
        for (int j_ = 0; j_ < 2; ++j_)                                                \
            _Pragma("unroll")                                                         \
            for (int ks_ = 0; ks_ < 2; ++ks_)                                         \
                acc[(mh) * 4 + i_][(nh) * 2 + j_] =                                   \
                    __builtin_amdgcn_mfma_f32_16x16x32_bf16(                          \
                        af_[i_][ks_], bv_[j_][ks_],                                   \
                        acc[(mh) * 4 + i_][(nh) * 2 + j_], 0, 0, 0);                  \
    __builtin_amdgcn_s_setprio(0);                                                    \
} while (0)

    // -------- prologue: K0 fully + K1 h0s; vmcnt(4) => K0 landed -------------------
    {
        char* a0 = sm;                  // buf0 A (halves at +0, +16384)
        char* b0 = sm + 32768;          // buf0 B
        char* a1 = sm + 65536;          // buf1 A
        char* b1 = sm + 65536 + 32768;  // buf1 B
        STAGE_HT(Abase, 0, 0, a0);
        STAGE_HT(Bbase, 0, 0, b0);
        STAGE_HT(Abase, 0, 1, a0 + 16384);
        STAGE_HT(Bbase, 0, 1, b0 + 16384);
        STAGE_HT(Abase, 1, 0, a1);
        STAGE_HT(Bbase, 1, 0, b1);
        asm volatile("s_waitcnt vmcnt(4)" ::: "memory");
        asm volatile("s_barrier" ::: "memory");
    }

    const int NT = K / 64;
    for (int t = 0; t < NT; ++t) {
        const int buf = t & 1;
        char* ldsA  = sm + buf * 65536;
        char* ldsB  = ldsA + 32768;
        char* ldsAn = sm + (buf ^ 1) * 65536;
        char* ldsBn = ldsAn + 32768;

        // q0: quad (0,0); stage tile t+1's h1 halves into the idle buffer
        PHASE(0, 0,
              if (t + 1 < NT) {
                  STAGE_HT(Abase, t + 1, 1, ldsAn + 16384);
                  STAGE_HT(Bbase, t + 1, 1, ldsBn + 16384);
              });
        asm volatile("s_barrier" ::: "memory");

        // q1: quad (0,1); no stage
        PHASE(0, 1, );
        asm volatile("s_barrier" ::: "memory");

        // q2: quad (1,0); stage A(t+2) h0 into current buffer's freed A-half0
        PHASE(1, 0,
              if (t + 2 < NT) { STAGE_HT(Abase, t + 2, 0, ldsA); });
        asm volatile("s_barrier" ::: "memory");

        // q3: quad (1,1); stage B(t+2) h0; counted wait covers all of tile t+1
        PHASE(1, 1,
              if (t + 2 < NT) { STAGE_HT(Bbase, t + 2, 0, ldsB); });
        if (t + 2 < NT) { asm volatile("s_waitcnt vmcnt(4)" ::: "memory"); }
        else            { asm volatile("s_waitcnt vmcnt(0)" ::: "memory"); }
        asm volatile("s_barrier" ::: "memory");
    }

    // -------- epilogue: C/D layout col=lane&15, row=(lane>>4)*4+reg ----------------
    const int erow = (lane >> 4) * 4;
    const int ecol = lane & 15;
#pragma unroll
    for (int mh = 0; mh < 2; ++mh)
#pragma unroll
        for (int i = 0; i < 4; ++i)
#pragma unroll
            for (int nh = 0; nh < 2; ++nh)
#pragma unroll
                for (int j = 0; j < 2; ++j)
#pragma unroll
                    for (int r = 0; r < 4; ++r) {
                        long row = trow0 + mh * 128 + wm * 64 + i * 16 + erow + r;
                        long col = tcol0 + nh * 128 + wn * 32 + j * 16 + ecol;
                        C[row * N + col] = acc[mh * 4 + i][nh * 2 + j][r] * scale;
                    }
#undef PHASE
#undef STAGE_HT
}

// -----------------------------------------------------------------------------------
extern "C" void kernel_launch(void* const* d_in, const int* in_sizes, int n_in,
                              void* d_out, int out_size, void* d_ws, size_t ws_size,
                              hipStream_t stream) {
    const int*   x    = (const int*)d_in[0];
    const float* emb  = (const float*)d_in[1];
    const float* wq   = (const float*)d_in[2];
    const float* wk   = (const float*)d_in[3];
    const float* wv   = (const float*)d_in[4];
    const float* wo   = (const float*)d_in[5];
    const float* wout = (const float*)d_in[6];
    float* logits = (float*)d_out;

    char* ws = (char*)d_ws;
    size_t off = 0;
    auto alloc = [&](size_t bytes) {
        char* p = ws + off;
        off += (bytes + 255) & ~(size_t)255;
        return p;
    };
    bf16_t* hb    = (bf16_t*)alloc((size_t)BT * DIM * 2);
    bf16_t* qb    = (bf16_t*)alloc((size_t)BT * DIM * 2);
    bf16_t* kb    = (bf16_t*)alloc((size_t)BT * DIM * 2);
    bf16_t* vtb   = (bf16_t*)alloc((size_t)BATCH * DIM * SEQ * 2);
    bf16_t* attnb = (bf16_t*)alloc((size_t)BATCH * SEQ * SEQ * 2);
    bf16_t* o1b   = (bf16_t*)alloc((size_t)BT * DIM * 2);
    bf16_t* o2b   = (bf16_t*)alloc((size_t)BT * DIM * 2);
    bf16_t* wqb   = (bf16_t*)alloc((size_t)DIM * DIM * 2);
    bf16_t* wkb   = (bf16_t*)alloc((size_t)DIM * DIM * 2);
    bf16_t* wvb   = (bf16_t*)alloc((size_t)DIM * DIM * 2);
    bf16_t* wob   = (bf16_t*)alloc((size_t)DIM * DIM * 2);
    bf16_t* woutb = (bf16_t*)alloc((size_t)VOCAB * DIM * 2);

    {
        int n4 = DIM * DIM / 4;
        cast_f32_to_bf16<<<n4 / 256, 256, 0, stream>>>(wq, wqb, n4);
        cast_f32_to_bf16<<<n4 / 256, 256, 0, stream>>>(wk, wkb, n4);
        cast_f32_to_bf16<<<n4 / 256, 256, 0, stream>>>(wv, wvb, n4);
        cast_f32_to_bf16<<<n4 / 256, 256, 0, stream>>>(wo, wob, n4);
        int n4o = VOCAB * DIM / 4;
        cast_f32_to_bf16<<<n4o / 256, 256, 0, stream>>>(wout, woutb, n4o);
    }

    embed_gather<<<BT, 256, 0, stream>>>(x, emb, hb);

    dim3 blk(256);
    gemm_bt<0, bf16_t><<<dim3(DIM / 128, BT / 128, 1), blk, 0, stream>>>(
        hb, wqb, qb, BT, DIM, DIM, 0, 0, 0, 0.01f);
    gemm_bt<0, bf16_t><<<dim3(DIM / 128, BT / 128, 1), blk, 0, stream>>>(
        hb, wkb, kb, BT, DIM, DIM, 0, 0, 0, 0.01f);
    gemm_bt<0, bf16_t><<<dim3(SEQ / 128, DIM / 128, BATCH), blk, 0, stream>>>(
        wvb, hb, vtb, DIM, SEQ, DIM, 0, (long)SEQ * DIM, (long)DIM * SEQ, 0.1f);
    gemm_bt<1, bf16_t><<<dim3(SEQ / 128, SEQ / 128, BATCH), blk, 0, stream>>>(
        qb, kb, attnb, SEQ, SEQ, DIM,
        (long)SEQ * DIM, (long)SEQ * DIM, (long)SEQ * SEQ, 0.01f);
    gemm_bt<0, bf16_t><<<dim3(DIM / 128, SEQ / 128, BATCH), blk, 0, stream>>>(
        attnb, vtb, o1b, SEQ, DIM, SEQ,
        (long)SEQ * SEQ, (long)DIM * SEQ, (long)SEQ * DIM, 0.01f);
    gemm_bt<0, bf16_t><<<dim3(DIM / 128, BT / 128, 1), blk, 0, stream>>>(
        o1b, wob, o2b, BT, DIM, DIM, 0, 0, 0, 0.1f);

    // logits: 256x256 8-phase; grid 1-D = 32 * 125 = 4000 blocks x 512 threads
    gemm_bt_256<<<(BT / 256) * (VOCAB / 256), 512, 0, stream>>>(
        o2b, woutb, logits, VOCAB, DIM, 1.0f);
}